// Round 4
// baseline (311.023 us; speedup 1.0000x reference)
//
#include <hip/hip_runtime.h>

typedef unsigned short u16;
typedef __bf16 bf16x8 __attribute__((ext_vector_type(8)));
typedef float f32x4 __attribute__((ext_vector_type(4)));

#define D_MODEL 1024
#define NH 16
#define DH 64
#define BB 2
#define SS 2048

#if __has_builtin(__builtin_amdgcn_exp2f)
#define EXP2f(x) __builtin_amdgcn_exp2f(x)
#else
#define EXP2f(x) exp2f(x)
#endif

__device__ __forceinline__ u16 f2bf_fast(float f) {
    union { float f; unsigned int u; } v; v.f = f;
    return (u16)((v.u + 0x8000u) >> 16);
}
// pack 8 fp32 -> 8 bf16 (half-up): 8 add + 4 perm
__device__ __forceinline__ uint4 pack8(const float4& a, const float4& b) {
    unsigned int a0 = __float_as_uint(a.x) + 0x8000u, a1 = __float_as_uint(a.y) + 0x8000u;
    unsigned int a2 = __float_as_uint(a.z) + 0x8000u, a3 = __float_as_uint(a.w) + 0x8000u;
    unsigned int b0 = __float_as_uint(b.x) + 0x8000u, b1 = __float_as_uint(b.y) + 0x8000u;
    unsigned int b2 = __float_as_uint(b.z) + 0x8000u, b3 = __float_as_uint(b.w) + 0x8000u;
    uint4 r;
    r.x = __builtin_amdgcn_perm(a1, a0, 0x07060302);
    r.y = __builtin_amdgcn_perm(a3, a2, 0x07060302);
    r.z = __builtin_amdgcn_perm(b1, b0, 0x07060302);
    r.w = __builtin_amdgcn_perm(b3, b2, 0x07060302);
    return r;
}

__device__ __forceinline__ void gld16(const void* g, void* l) {
    __builtin_amdgcn_global_load_lds(
        (const __attribute__((address_space(1))) unsigned int*)g,
        (__attribute__((address_space(3))) unsigned int*)l, 16, 0, 0);
}

// Fused prep: blocks [0,2048) convert Wq/Wk/Wv/Wo fp32->bf16 (512 blocks per
// weight); blocks [2048,3072) pack mask int32 -> bitmask pm[B*S][S/64].
__global__ __launch_bounds__(256) void prep_kernel(
    const float* __restrict__ Wq, const float* __restrict__ Wk,
    const float* __restrict__ Wv, const float* __restrict__ Wo, u16* __restrict__ cW,
    const int* __restrict__ mask, unsigned long long* __restrict__ pm)
{
    int bid = blockIdx.x;
    if (bid < 2048) {
        int z = bid >> 9, x = bid & 511;
        const float* src = (z == 0) ? Wq : (z == 1) ? Wk : (z == 2) ? Wv : Wo;
        u16* dst = cW + (size_t)z * D_MODEL * D_MODEL;
        size_t base = ((size_t)x * 256 + threadIdx.x) * 8;
        float4 a = *reinterpret_cast<const float4*>(src + base);
        float4 b = *reinterpret_cast<const float4*>(src + base + 4);
        *reinterpret_cast<uint4*>(dst + base) = pack8(a, b);
    } else {
        int x = bid - 2048;
        int gw = (x * 256 + threadIdx.x) >> 6;   // 0..4095
        int l = threadIdx.x & 63;
#pragma unroll 4
        for (int i = 0; i < 32; ++i) {
            int widx = gw * 32 + i;
            int m = mask[(size_t)widx * 64 + l];
            unsigned long long bits = __ballot(m != 0);
            if (l == 0) pm[widx] = bits;
        }
    }
}

// m97-structure NT GEMM, bf16 A via gld16 (oproj path).
// C[m,n] = (sum_k A[m,k]*W[n,k] + bias[n]) * oscale, fp32 direct scatter.
__device__ void gemm_bb_f32out(const u16* __restrict__ A, const u16* __restrict__ W,
                               const float* __restrict__ bias, float* outp, float oscale)
{
    __shared__ __align__(16) u16 smem[128 * 144];
    u16* lA = smem;
    u16* lW = smem + 128 * 64;
    const int t = threadIdx.x, w = t >> 6, l = t & 63;
    const int blockM = blockIdx.x * 128, blockN = blockIdx.y * 128;
    const int lrow = l >> 3, lcol = (l & 7) * 8;
    const int quad = l >> 4, c16 = l & 15;

    f32x4 acc[4][4] = {};

    for (int kt = 0; kt < 16; ++kt) {
        __syncthreads();
#pragma unroll
        for (int i = 0; i < 4; ++i) {
            int c = w * 4 + i;
            int row = c * 8 + lrow;
            gld16(A + (size_t)(blockM + row) * 1024 + kt * 64 + lcol, &lA[c * 512]);
            gld16(W + (size_t)(blockN + row) * 1024 + kt * 64 + lcol, &lW[c * 512]);
        }
        __syncthreads();
#pragma unroll
        for (int ks = 0; ks < 2; ++ks) {
            bf16x8 af[4], bfr[4];
#pragma unroll
            for (int mi = 0; mi < 4; ++mi)
                af[mi] = *reinterpret_cast<const bf16x8*>(
                    &lA[((w & 1) * 64 + mi * 16 + c16) * 64 + ks * 32 + quad * 8]);
#pragma unroll
            for (int ni = 0; ni < 4; ++ni)
                bfr[ni] = *reinterpret_cast<const bf16x8*>(
                    &lW[((w >> 1) * 64 + ni * 16 + c16) * 64 + ks * 32 + quad * 8]);
#pragma unroll
            for (int mi = 0; mi < 4; ++mi)
#pragma unroll
                for (int ni = 0; ni < 4; ++ni)
                    acc[mi][ni] = __builtin_amdgcn_mfma_f32_16x16x32_bf16(
                        af[mi], bfr[ni], acc[mi][ni], 0, 0, 0);
        }
    }

    const int m0 = blockM + (w & 1) * 64, n0 = blockN + (w >> 1) * 64;
#pragma unroll
    for (int ni = 0; ni < 4; ++ni) {
        int n = n0 + ni * 16 + c16;
        float bv = bias[n];
#pragma unroll
        for (int mi = 0; mi < 4; ++mi) {
#pragma unroll
            for (int r = 0; r < 4; ++r) {
                int m = m0 + mi * 16 + quad * 4 + r;
                float val = (acc[mi][ni][r] + bv) * oscale;
                outp[(size_t)m * 1024 + n] = val;
            }
        }
    }
}

// QKV GEMM with fused fp32->bf16 A conversion: A is raw fp32 input (q/k/v),
// reg-staged (float4 x2 -> pack8 -> ds_write_b128, same LDS layout as gld16
// would produce: chunk c, lane l -> lA[c*512 + l*8]). W stays gld16.
// Epilogue restages tile in LDS -> coalesced [b,h,s,dh] bf16 writes.
__device__ void gemm_qkv(const float* __restrict__ A, const u16* __restrict__ W,
                         const float* __restrict__ bias, u16* __restrict__ outp,
                         float oscale)
{
    __shared__ __align__(16) u16 smem[128 * 144];   // staging: 2x 128*64; restage: 128*136
    u16* lA = smem;
    u16* lW = smem + 128 * 64;
    const int t = threadIdx.x, w = t >> 6, l = t & 63;
    const int blockM = blockIdx.x * 128, blockN = blockIdx.y * 128;
    const int lrow = l >> 3, lcol = (l & 7) * 8;
    const int quad = l >> 4, c16 = l & 15;

    f32x4 acc[4][4] = {};

    for (int kt = 0; kt < 16; ++kt) {
        __syncthreads();
        // A: issue all fp32 loads first (VMEM batch), W: gld16 direct-to-LDS
        float4 fa[4][2];
#pragma unroll
        for (int i = 0; i < 4; ++i) {
            int c = w * 4 + i;
            int row = c * 8 + lrow;
            const float* srcA = A + (size_t)(blockM + row) * 1024 + kt * 64 + lcol;
            fa[i][0] = *reinterpret_cast<const float4*>(srcA);
            fa[i][1] = *reinterpret_cast<const float4*>(srcA + 4);
        }
#pragma unroll
        for (int i = 0; i < 4; ++i) {
            int c = w * 4 + i;
            int row = c * 8 + lrow;
            gld16(W + (size_t)(blockN + row) * 1024 + kt * 64 + lcol, &lW[c * 512]);
        }
#pragma unroll
        for (int i = 0; i < 4; ++i) {
            int c = w * 4 + i;
            *reinterpret_cast<uint4*>(&lA[c * 512 + l * 8]) = pack8(fa[i][0], fa[i][1]);
        }
        __syncthreads();
#pragma unroll
        for (int ks = 0; ks < 2; ++ks) {
            bf16x8 af[4], bfr[4];
#pragma unroll
            for (int mi = 0; mi < 4; ++mi)
                af[mi] = *reinterpret_cast<const bf16x8*>(
                    &lA[((w & 1) * 64 + mi * 16 + c16) * 64 + ks * 32 + quad * 8]);
#pragma unroll
            for (int ni = 0; ni < 4; ++ni)
                bfr[ni] = *reinterpret_cast<const bf16x8*>(
                    &lW[((w >> 1) * 64 + ni * 16 + c16) * 64 + ks * 32 + quad * 8]);
#pragma unroll
            for (int mi = 0; mi < 4; ++mi)
#pragma unroll
                for (int ni = 0; ni < 4; ++ni)
                    acc[mi][ni] = __builtin_amdgcn_mfma_f32_16x16x32_bf16(
                        af[mi], bfr[ni], acc[mi][ni], 0, 0, 0);
        }
    }

    // restage through LDS (stride 136) -> full-line [b,h,s,dh] writes
    __syncthreads();
    const int m_base = (w & 1) * 64, n_base = (w >> 1) * 64;
#pragma unroll
    for (int ni = 0; ni < 4; ++ni) {
        int n_local = n_base + ni * 16 + c16;
        float bv = bias[blockN + n_local];
#pragma unroll
        for (int mi = 0; mi < 4; ++mi)
#pragma unroll
            for (int r = 0; r < 4; ++r) {
                int m_local = m_base + mi * 16 + quad * 4 + r;
                smem[m_local * 136 + n_local] =
                    f2bf_fast((acc[mi][ni][r] + bv) * oscale);
            }
    }
    __syncthreads();
    const int bb = blockM >> 11, s_base = blockM & 2047;
#pragma unroll
    for (int i = 0; i < 8; ++i) {
        int idx = t + i * 256;
        int mrow = idx >> 4, ch = idx & 15;
        uint4 val = *reinterpret_cast<const uint4*>(&smem[mrow * 136 + ch * 8]);
        int gn = blockN + ch * 8;
        int hh = gn >> 6, dh = gn & 63;
        *reinterpret_cast<uint4*>(
            outp + (((size_t)(bb * NH + hh)) * SS + s_base + mrow) * DH + dh) = val;
    }
}

__global__ __launch_bounds__(256) void qkv_kernel(
    const float* __restrict__ q, const float* __restrict__ k, const float* __restrict__ v,
    const u16* __restrict__ cW,
    const float* __restrict__ bq, const float* __restrict__ bk, const float* __restrict__ bv,
    u16* __restrict__ qh, u16* __restrict__ kh, u16* __restrict__ vh)
{
    int z = blockIdx.z;
    const float* A = (z == 0) ? q : (z == 1) ? k : v;
    const u16* W = cW + (size_t)z * D_MODEL * D_MODEL;
    const float* bias = (z == 0) ? bq : (z == 1) ? bk : bv;
    u16* out = (z == 0) ? qh : (z == 1) ? kh : vh;
    // fold 1/sqrt(dh) AND log2(e) into Q so softmax uses raw v_exp_f32 (exp2)
    float oscale = (z == 0) ? 0.18033688011112042f : 1.0f;
    gemm_qkv(A, W, bias, out, oscale);
}

__global__ __launch_bounds__(256) void oproj_kernel(
    const u16* __restrict__ A, const u16* __restrict__ cWo,
    const float* __restrict__ bo, float* __restrict__ out)
{
    gemm_bb_f32out(A, cWo, bo, out, 1.0f);
}

// Flash attention v2 (unchanged from round 2 — control): QBLK=128, 4 waves x
// 32 q-rows each, KVBLK=64. Each kf/vf LDS fragment read feeds 2 MFMAs.
// lP (128 rows, stride 72) triple-duties: Q stage / P tile / O restage.
// LDS = (64+64+128)*72*2 = 36864 B -> 2 blocks/CU resident (512 blocks).
__global__ __launch_bounds__(256, 2) void attn_kernel(
    const u16* __restrict__ qh, const u16* __restrict__ kh, const u16* __restrict__ vh,
    const unsigned long long* __restrict__ pm, u16* __restrict__ ao)
{
    __shared__ __align__(16) u16 lK[64 * 72];
    __shared__ __align__(16) u16 lVt[64 * 72];   // Vt[d][sk], stride 72
    __shared__ __align__(16) u16 lP[128 * 72];   // Q stage / P[q][sk] / O restage

    const int t = threadIdx.x, w = t >> 6, l = t & 63;
    const int qt = blockIdx.x, h = blockIdx.y, b = blockIdx.z;
    const int sq0 = qt * 128;
    const size_t headbase = ((size_t)(b * NH + h)) * SS * DH;
    const int quad = l >> 4, c16 = l & 15;
    const int lrow = l >> 3, lcol = (l & 7) * 8;
    const int vd2 = t & 31, vg = t >> 5;

    // ---- stage Q once (pre-scaled by 0.125*log2e at projection) ----
#pragma unroll
    for (int i = 0; i < 4; ++i) {
        int row = (w * 4 + i) * 8 + lrow;
        uint4 rq = *reinterpret_cast<const uint4*>(
            qh + headbase + (size_t)(sq0 + row) * DH + lcol);
        *reinterpret_cast<uint4*>(&lP[row * 72 + lcol]) = rq;
    }
    __asm__ volatile("s_waitcnt lgkmcnt(0)" ::: "memory");
    bf16x8 qf[2][2];
#pragma unroll
    for (int g = 0; g < 2; ++g)
#pragma unroll
        for (int ks = 0; ks < 2; ++ks)
            qf[g][ks] = *reinterpret_cast<const bf16x8*>(
                &lP[(w * 32 + g * 16 + c16) * 72 + ks * 32 + quad * 8]);

    f32x4 oAcc[2][4] = {};
    float rsumAcc[2] = {0.f, 0.f};
    const size_t pmrow0 = ((size_t)b * SS + sq0 + w * 32 + c16) * 32;
    const size_t pmrow1 = pmrow0 + 16 * 32;

    // prime kt=0 loads
    uint4 rk[2];
    unsigned int rvv[8];
    unsigned long long mw_cur0, mw_cur1, mw_next0, mw_next1;
#pragma unroll
    for (int i = 0; i < 2; ++i) {
        int row = (w * 2 + i) * 8 + lrow;
        rk[i] = *reinterpret_cast<const uint4*>(kh + headbase + (size_t)row * DH + lcol);
    }
#pragma unroll
    for (int e = 0; e < 8; ++e)
        rvv[e] = *reinterpret_cast<const unsigned int*>(
            vh + headbase + (size_t)(vg * 8 + e) * DH + vd2 * 2);
    mw_cur0 = pm[pmrow0 + 0];
    mw_cur1 = pm[pmrow1 + 0];

    for (int kt = 0; kt < 32; ++kt) {
        __syncthreads();  // A: prev compute's lK/lVt reads done
        // ---- store staged tiles ----
#pragma unroll
        for (int i = 0; i < 2; ++i) {
            int row = (w * 2 + i) * 8 + lrow;
            *reinterpret_cast<uint4*>(&lK[row * 72 + lcol]) = rk[i];
        }
        {
            uint4 cA, cB;
            cA.x = __builtin_amdgcn_perm(rvv[1], rvv[0], 0x05040100);
            cA.y = __builtin_amdgcn_perm(rvv[3], rvv[2], 0x05040100);
            cA.z = __builtin_amdgcn_perm(rvv[5], rvv[4], 0x05040100);
            cA.w = __builtin_amdgcn_perm(rvv[7], rvv[6], 0x05040100);
            cB.x = __builtin_amdgcn_perm(rvv[1], rvv[0], 0x07060302);
            cB.y = __builtin_amdgcn_perm(rvv[3], rvv[2], 0x07060302);
            cB.z = __builtin_amdgcn_perm(rvv[5], rvv[4], 0x07060302);
            cB.w = __builtin_amdgcn_perm(rvv[7], rvv[6], 0x07060302);
            *reinterpret_cast<uint4*>(&lVt[(2 * vd2) * 72 + vg * 8]) = cA;
            *reinterpret_cast<uint4*>(&lVt[(2 * vd2 + 1) * 72 + vg * 8]) = cB;
        }
        __syncthreads();  // B
        // ---- issue kt+1 loads (in flight during compute) ----
        {
            int ktn = (kt < 31) ? kt + 1 : kt;
            const int sk0n = ktn * 64;
#pragma unroll
            for (int i = 0; i < 2; ++i) {
                int row = (w * 2 + i) * 8 + lrow;
                rk[i] = *reinterpret_cast<const uint4*>(
                    kh + headbase + (size_t)(sk0n + row) * DH + lcol);
            }
#pragma unroll
            for (int e = 0; e < 8; ++e)
                rvv[e] = *reinterpret_cast<const unsigned int*>(
                    vh + headbase + (size_t)(sk0n + vg * 8 + e) * DH + vd2 * 2);
            mw_next0 = pm[pmrow0 + ktn];
            mw_next1 = pm[pmrow1 + ktn];
        }

        // ---- S^T = K Q^T : lane holds S^T[sk=ni*16+quad*4+r][q=w*32+g*16+c16]
        f32x4 sAcc[2][4] = {};
        __builtin_amdgcn_s_setprio(1);
#pragma unroll
        for (int ks = 0; ks < 2; ++ks) {
#pragma unroll
            for (int ni = 0; ni < 4; ++ni) {
                bf16x8 kf = *reinterpret_cast<const bf16x8*>(
                    &lK[(ni * 16 + c16) * 72 + ks * 32 + quad * 8]);
                sAcc[0][ni] = __builtin_amdgcn_mfma_f32_16x16x32_bf16(
                    kf, qf[0][ks], sAcc[0][ni], 0, 0, 0);
                sAcc[1][ni] = __builtin_amdgcn_mfma_f32_16x16x32_bf16(
                    kf, qf[1][ks], sAcc[1][ni], 0, 0, 0);
            }
        }
        __builtin_amdgcn_s_setprio(0);

        // ---- mask + exp2 + packed P store (2 groups x 4 x ds_write_b64) ----
#pragma unroll
        for (int g = 0; g < 2; ++g) {
            unsigned long long mw = g ? mw_cur1 : mw_cur0;
            unsigned long long mq = mw >> (quad * 4);
            unsigned int mlo = (unsigned int)mq, mhi = (unsigned int)(mq >> 32);
            float rs = 0.f;
#pragma unroll
            for (int ni = 0; ni < 4; ++ni) {
                unsigned int half = (ni < 2) ? mlo : mhi;
                unsigned int sh = (ni & 1) * 16;
                unsigned int w0, w1;
                {
                    float p0 = ((half >> (sh + 0)) & 1u) ? EXP2f(sAcc[g][ni][0]) : 0.f;
                    float p1 = ((half >> (sh + 1)) & 1u) ? EXP2f(sAcc[g][ni][1]) : 0.f;
                    float p2 = ((half >> (sh + 2)) & 1u) ? EXP2f(sAcc[g][ni][2]) : 0.f;
                    float p3 = ((half >> (sh + 3)) & 1u) ? EXP2f(sAcc[g][ni][3]) : 0.f;
                    rs += (p0 + p1) + (p2 + p3);
                    w0 = __builtin_amdgcn_perm(__float_as_uint(p1) + 0x8000u,
                                               __float_as_uint(p0) + 0x8000u, 0x07060302);
                    w1 = __builtin_amdgcn_perm(__float_as_uint(p3) + 0x8000u,
                                               __float_as_uint(p2) + 0x8000u, 0x07060302);
                }
                uint2 pv; pv.x = w0; pv.y = w1;
                *reinterpret_cast<uint2*>(
                    &lP[(w * 32 + g * 16 + c16) * 72 + ni * 16 + quad * 4]) = pv;
            }
            if (g == 0) rsumAcc[0] += rs; else rsumAcc[1] += rs;
        }
        mw_cur0 = mw_next0; mw_cur1 = mw_next1;
        // wave-private lP RAW: drain DS queue, no cross-wave barrier needed
        __asm__ volatile("s_waitcnt lgkmcnt(0)" ::: "memory");

        // ---- O += P @ V : each vf read feeds both q-groups ----
        __builtin_amdgcn_s_setprio(1);
#pragma unroll
        for (int ks = 0; ks < 2; ++ks) {
            bf16x8 pf0 = *reinterpret_cast<const bf16x8*>(
                &lP[(w * 32 + c16) * 72 + ks * 32 + quad * 8]);
            bf16x8 pf1 = *reinterpret_cast<const bf16x8*>(
                &lP[(w * 32 + 16 + c16) * 72 + ks * 32 + quad * 8]);
#pragma unroll
            for (int no = 0; no < 4; ++no) {
                bf16x8 vf = *reinterpret_cast<const bf16x8*>(
                    &lVt[(no * 16 + c16) * 72 + ks * 32 + quad * 8]);
                oAcc[0][no] = __builtin_amdgcn_mfma_f32_16x16x32_bf16(
                    pf0, vf, oAcc[0][no], 0, 0, 0);
                oAcc[1][no] = __builtin_amdgcn_mfma_f32_16x16x32_bf16(
                    pf1, vf, oAcc[1][no], 0, 0, 0);
            }
        }
        __builtin_amdgcn_s_setprio(0);
    }

    // ---- epilogue: row-sum reduce, normalize, restage O in lP, write ----
    float linv[2][4];
#pragma unroll
    for (int g = 0; g < 2; ++g) {
        float s = (g == 0) ? rsumAcc[0] : rsumAcc[1];
        s += __shfl_xor(s, 16);
        s += __shfl_xor(s, 32);
        float rinv = 1.0f / s;
#pragma unroll
        for (int r = 0; r < 4; ++r)
            linv[g][r] = __shfl(rinv, quad * 4 + r);
    }
#pragma unroll
    for (int g = 0; g < 2; ++g)
#pragma unroll
        for (int no = 0; no < 4; ++no)
#pragma unroll
            for (int r = 0; r < 4; ++r)
                lP[(w * 32 + g * 16 + quad * 4 + r) * 72 + no * 16 + c16] =
                    f2bf_fast(oAcc[g][no][r] * linv[g][r]);
    __syncthreads();
#pragma unroll
    for (int i = 0; i < 4; ++i) {
        int idx = t + i * 256;
        int row = idx >> 3, ch = idx & 7;
        uint4 val = *reinterpret_cast<const uint4*>(&lP[row * 72 + ch * 8]);
        *reinterpret_cast<uint4*>(
            ao + ((size_t)b * SS + sq0 + row) * D_MODEL + h * DH + ch * 8) = val;
    }
}

extern "C" void kernel_launch(void* const* d_in, const int* in_sizes, int n_in,
                              void* d_out, int out_size, void* d_ws, size_t ws_size,
                              hipStream_t stream)
{
    const float* q    = (const float*)d_in[0];
    const float* k    = (const float*)d_in[1];
    const float* v    = (const float*)d_in[2];
    const int*   mask = (const int*)d_in[3];
    const float* Wq   = (const float*)d_in[4];
    const float* bq   = (const float*)d_in[5];
    const float* Wk   = (const float*)d_in[6];
    const float* bk   = (const float*)d_in[7];
    const float* Wv   = (const float*)d_in[8];
    const float* bv   = (const float*)d_in[9];
    const float* Wo   = (const float*)d_in[10];
    const float* bo   = (const float*)d_in[11];

    const size_t T4M = (size_t)BB * SS * D_MODEL;  // 4,194,304 elems
    u16* qh = (u16*)d_ws;                          // [B][NH][S][DH] bf16 (Q pre-scaled)
    u16* kh = qh + T4M;
    u16* vh = kh + T4M;
    u16* ao = vh + T4M;                            // [B][S][D] bf16
    u16* cW = ao + T4M;                            // 4 x 1M bf16 (Wq,Wk,Wv,Wo)
    unsigned long long* pm = (unsigned long long*)(cW + 4 * (size_t)D_MODEL * D_MODEL);
    float* out = (float*)d_out;

    prep_kernel<<<3072, 256, 0, stream>>>(Wq, Wk, Wv, Wo, cW, mask, pm);
    qkv_kernel<<<dim3(32, 8, 3), 256, 0, stream>>>(q, k, v, cW, bq, bk, bv, qh, kh, vh);
    attn_kernel<<<dim3(16, NH, BB), 256, 0, stream>>>(qh, kh, vh, pm, ao);
    oproj_kernel<<<dim3(32, 8), 256, 0, stream>>>(ao, cW + 3 * (size_t)D_MODEL * D_MODEL, bo, out);
}

// Round 10
// 302.504 us; speedup vs baseline: 1.0282x; 1.0282x over previous
//
#include <hip/hip_runtime.h>

typedef unsigned short u16;
typedef __bf16 bf16x8 __attribute__((ext_vector_type(8)));
typedef float f32x4 __attribute__((ext_vector_type(4)));

#define D_MODEL 1024
#define NH 16
#define DH 64
#define BB 2
#define SS 2048

#if __has_builtin(__builtin_amdgcn_exp2f)
#define EXP2f(x) __builtin_amdgcn_exp2f(x)
#else
#define EXP2f(x) exp2f(x)
#endif

__device__ __forceinline__ u16 f2bf_fast(float f) {
    union { float f; unsigned int u; } v; v.f = f;
    return (u16)((v.u + 0x8000u) >> 16);
}
// pack 8 fp32 -> 8 bf16 (half-up): 8 add + 4 perm
__device__ __forceinline__ uint4 pack8(const float4& a, const float4& b) {
    unsigned int a0 = __float_as_uint(a.x) + 0x8000u, a1 = __float_as_uint(a.y) + 0x8000u;
    unsigned int a2 = __float_as_uint(a.z) + 0x8000u, a3 = __float_as_uint(a.w) + 0x8000u;
    unsigned int b0 = __float_as_uint(b.x) + 0x8000u, b1 = __float_as_uint(b.y) + 0x8000u;
    unsigned int b2 = __float_as_uint(b.z) + 0x8000u, b3 = __float_as_uint(b.w) + 0x8000u;
    uint4 r;
    r.x = __builtin_amdgcn_perm(a1, a0, 0x07060302);
    r.y = __builtin_amdgcn_perm(a3, a2, 0x07060302);
    r.z = __builtin_amdgcn_perm(b1, b0, 0x07060302);
    r.w = __builtin_amdgcn_perm(b3, b2, 0x07060302);
    return r;
}

__device__ __forceinline__ void gld16(const void* g, void* l) {
    __builtin_amdgcn_global_load_lds(
        (const __attribute__((address_space(1))) unsigned int*)g,
        (__attribute__((address_space(3))) unsigned int*)l, 16, 0, 0);
}

// Fused prep:
//   blocks [0,2048)    : Wq/Wk/Wv/Wo fp32 -> cW bf16 (512 blocks per weight)
//   blocks [2048,8192) : q,k,v fp32 -> qb bf16 (2048 blocks per tensor)
//   blocks [8192,9216) : mask int32 -> bitmask pm[B*S][S/64]
__global__ __launch_bounds__(256) void prep_kernel(
    const float* __restrict__ Wq, const float* __restrict__ Wk,
    const float* __restrict__ Wv, const float* __restrict__ Wo, u16* __restrict__ cW,
    const float* __restrict__ q, const float* __restrict__ k,
    const float* __restrict__ v, u16* __restrict__ qb,
    const int* __restrict__ mask, unsigned long long* __restrict__ pm)
{
    int bid = blockIdx.x;
    if (bid < 2048) {
        int z = bid >> 9, x = bid & 511;
        const float* src = (z == 0) ? Wq : (z == 1) ? Wk : (z == 2) ? Wv : Wo;
        u16* dst = cW + (size_t)z * D_MODEL * D_MODEL;
        size_t base = ((size_t)x * 256 + threadIdx.x) * 8;
        float4 a = *reinterpret_cast<const float4*>(src + base);
        float4 b = *reinterpret_cast<const float4*>(src + base + 4);
        *reinterpret_cast<uint4*>(dst + base) = pack8(a, b);
    } else if (bid < 8192) {
        int x = bid - 2048;
        int z = x >> 11, xx = x & 2047;
        const float* src = (z == 0) ? q : (z == 1) ? k : v;
        u16* dst = qb + (size_t)z * BB * SS * D_MODEL;
        size_t base = ((size_t)xx * 256 + threadIdx.x) * 8;
        float4 a = *reinterpret_cast<const float4*>(src + base);
        float4 b = *reinterpret_cast<const float4*>(src + base + 4);
        *reinterpret_cast<uint4*>(dst + base) = pack8(a, b);
    } else {
        int x = bid - 8192;
        int gw = (x * 256 + threadIdx.x) >> 6;   // 0..4095
        int l = threadIdx.x & 63;
#pragma unroll 4
        for (int i = 0; i < 32; ++i) {
            int widx = gw * 32 + i;
            int m = mask[(size_t)widx * 64 + l];
            unsigned long long bits = __ballot(m != 0);
            if (l == 0) pm[widx] = bits;
        }
    }
}

// m97-structure NT GEMM, all-bf16 operands (Round-2 proven): gld16 width-16
// staging, stride-64 LDS, 2-barrier K-loop.
// C[m,n] = (sum_k A[m,k]*W[n,k] + bias[n]) * oscale.
// QKV=1: epilogue restages tile in LDS -> coalesced [b,h,s,dh] bf16 writes.
// QKV=0: direct fp32 scatter (64-B chunks).
template<int OF32, int QKV>
__device__ void gemm_bb(const u16* __restrict__ A, const u16* __restrict__ W,
                        const float* __restrict__ bias, void* outp, float oscale)
{
    __shared__ __align__(16) u16 smem[128 * 144];   // staging: 2x 128*64; restage: 128*136
    u16* lA = smem;
    u16* lW = smem + 128 * 64;
    const int t = threadIdx.x, w = t >> 6, l = t & 63;
    const int blockM = blockIdx.x * 128, blockN = blockIdx.y * 128;
    const int lrow = l >> 3, lcol = (l & 7) * 8;
    const int quad = l >> 4, c16 = l & 15;

    f32x4 acc[4][4] = {};

    for (int kt = 0; kt < 16; ++kt) {
        __syncthreads();
#pragma unroll
        for (int i = 0; i < 4; ++i) {
            int c = w * 4 + i;
            int row = c * 8 + lrow;
            gld16(A + (size_t)(blockM + row) * 1024 + kt * 64 + lcol, &lA[c * 512]);
            gld16(W + (size_t)(blockN + row) * 1024 + kt * 64 + lcol, &lW[c * 512]);
        }
        __syncthreads();
#pragma unroll
        for (int ks = 0; ks < 2; ++ks) {
            bf16x8 af[4], bfr[4];
#pragma unroll
            for (int mi = 0; mi < 4; ++mi)
                af[mi] = *reinterpret_cast<const bf16x8*>(
                    &lA[((w & 1) * 64 + mi * 16 + c16) * 64 + ks * 32 + quad * 8]);
#pragma unroll
            for (int ni = 0; ni < 4; ++ni)
                bfr[ni] = *reinterpret_cast<const bf16x8*>(
                    &lW[((w >> 1) * 64 + ni * 16 + c16) * 64 + ks * 32 + quad * 8]);
#pragma unroll
            for (int mi = 0; mi < 4; ++mi)
#pragma unroll
                for (int ni = 0; ni < 4; ++ni)
                    acc[mi][ni] = __builtin_amdgcn_mfma_f32_16x16x32_bf16(
                        af[mi], bfr[ni], acc[mi][ni], 0, 0, 0);
        }
    }

    if (QKV) {
        // restage through LDS (stride 136) -> full-line [b,h,s,dh] writes
        __syncthreads();
        const int m_base = (w & 1) * 64, n_base = (w >> 1) * 64;
#pragma unroll
        for (int ni = 0; ni < 4; ++ni) {
            int n_local = n_base + ni * 16 + c16;
            float bv = bias[blockN + n_local];
#pragma unroll
            for (int mi = 0; mi < 4; ++mi)
#pragma unroll
                for (int r = 0; r < 4; ++r) {
                    int m_local = m_base + mi * 16 + quad * 4 + r;
                    smem[m_local * 136 + n_local] =
                        f2bf_fast((acc[mi][ni][r] + bv) * oscale);
                }
        }
        __syncthreads();
        const int bb = blockM >> 11, s_base = blockM & 2047;
        u16* outb = (u16*)outp;
#pragma unroll
        for (int i = 0; i < 8; ++i) {
            int idx = t + i * 256;
            int mrow = idx >> 4, ch = idx & 15;
            uint4 val = *reinterpret_cast<const uint4*>(&smem[mrow * 136 + ch * 8]);
            int gn = blockN + ch * 8;
            int hh = gn >> 6, dh = gn & 63;
            *reinterpret_cast<uint4*>(
                outb + (((size_t)(bb * NH + hh)) * SS + s_base + mrow) * DH + dh) = val;
        }
        return;
    }

    const int m0 = blockM + (w & 1) * 64, n0 = blockN + (w >> 1) * 64;
#pragma unroll
    for (int ni = 0; ni < 4; ++ni) {
        int n = n0 + ni * 16 + c16;
        float bv = bias[n];
#pragma unroll
        for (int mi = 0; mi < 4; ++mi) {
#pragma unroll
            for (int r = 0; r < 4; ++r) {
                int m = m0 + mi * 16 + quad * 4 + r;
                float val = (acc[mi][ni][r] + bv) * oscale;
                ((float*)outp)[(size_t)m * 1024 + n] = val;
            }
        }
    }
}

__global__ __launch_bounds__(256) void qkv_kernel(
    const u16* __restrict__ qb, const u16* __restrict__ cW,
    const float* __restrict__ bq, const float* __restrict__ bk, const float* __restrict__ bv,
    u16* __restrict__ qh, u16* __restrict__ kh, u16* __restrict__ vh)
{
    int z = blockIdx.z;
    const u16* A = qb + (size_t)z * BB * SS * D_MODEL;
    const u16* W = cW + (size_t)z * D_MODEL * D_MODEL;
    const float* bias = (z == 0) ? bq : (z == 1) ? bk : bv;
    u16* out = (z == 0) ? qh : (z == 1) ? kh : vh;
    // fold 1/sqrt(dh) AND log2(e) into Q so softmax uses raw v_exp_f32 (exp2)
    float oscale = (z == 0) ? 0.18033688011112042f : 1.0f;
    gemm_bb<0, 1>(A, W, bias, out, oscale);
}

__global__ __launch_bounds__(256) void oproj_kernel(
    const u16* __restrict__ A, const u16* __restrict__ cWo,
    const float* __restrict__ bo, float* __restrict__ out)
{
    gemm_bb<1, 0>(A, cWo, bo, out, 1.0f);
}

// Flash attention v3: QBLK=128, 4 waves x 32 q-rows, KVBLK=64.
// K and Vt now stored FRAGMENT-LINEAR in LDS: chunk (ni*2+ks) holds 64
// lanes x 16 B, lane l = quad*16+c16 owns K[ni*16+c16][ks*32+quad*8..+8]
// (resp. Vt). All kf/vf reads are lane-linear contiguous ds_read_b128 ->
// conflict-free (stride-72 fragment reads were 8-way: bank 4((row+quad)%8)).
// K global source is pre-swizzled to the fragment mapping so the LDS write
// stays lane-linear too. lP (Q stage / P tile / O restage) unchanged.
__global__ __launch_bounds__(256, 2) void attn_kernel(
    const u16* __restrict__ qh, const u16* __restrict__ kh, const u16* __restrict__ vh,
    const unsigned long long* __restrict__ pm, u16* __restrict__ ao)
{
    __shared__ __align__(16) u16 lK[8 * 512];    // fragment-linear, 8 KB
    __shared__ __align__(16) u16 lVt[8 * 512];   // fragment-linear, 8 KB
    __shared__ __align__(16) u16 lP[128 * 72];   // Q stage / P[q][sk] / O restage

    const int t = threadIdx.x, w = t >> 6, l = t & 63;
    const int qt = blockIdx.x, h = blockIdx.y, b = blockIdx.z;
    const int sq0 = qt * 128;
    const size_t headbase = ((size_t)(b * NH + h)) * SS * DH;
    const int quad = l >> 4, c16 = l & 15;
    const int lrow = l >> 3, lcol = (l & 7) * 8;
    const int vd2 = t & 31, vg = t >> 5;

    // ---- stage Q once (pre-scaled by 0.125*log2e at projection) ----
#pragma unroll
    for (int i = 0; i < 4; ++i) {
        int row = (w * 4 + i) * 8 + lrow;
        uint4 rq = *reinterpret_cast<const uint4*>(
            qh + headbase + (size_t)(sq0 + row) * DH + lcol);
        *reinterpret_cast<uint4*>(&lP[row * 72 + lcol]) = rq;
    }
    __asm__ volatile("s_waitcnt lgkmcnt(0)" ::: "memory");
    bf16x8 qf[2][2];
#pragma unroll
    for (int g = 0; g < 2; ++g)
#pragma unroll
        for (int ks = 0; ks < 2; ++ks)
            qf[g][ks] = *reinterpret_cast<const bf16x8*>(
                &lP[(w * 32 + g * 16 + c16) * 72 + ks * 32 + quad * 8]);

    f32x4 oAcc[2][4] = {};
    float rsumAcc[2] = {0.f, 0.f};
    const size_t pmrow0 = ((size_t)b * SS + sq0 + w * 32 + c16) * 32;
    const size_t pmrow1 = pmrow0 + 16 * 32;

    // K fragment-mapped global coords: chunk c = w*2+i, lane l ->
    // row (c>>1)*16 + c16, cols (c&1)*32 + quad*8 (u16 units)
    const int kcol = quad * 8;

    // prime kt=0 loads
    uint4 rk[2];
    unsigned int rvv[8];
    unsigned long long mw_cur0, mw_cur1, mw_next0, mw_next1;
#pragma unroll
    for (int i = 0; i < 2; ++i) {
        int c = w * 2 + i;
        rk[i] = *reinterpret_cast<const uint4*>(
            kh + headbase + (size_t)((c >> 1) * 16 + c16) * DH + (c & 1) * 32 + kcol);
    }
#pragma unroll
    for (int e = 0; e < 8; ++e)
        rvv[e] = *reinterpret_cast<const unsigned int*>(
            vh + headbase + (size_t)(vg * 8 + e) * DH + vd2 * 2);
    mw_cur0 = pm[pmrow0 + 0];
    mw_cur1 = pm[pmrow1 + 0];

    // Vt fragment write coords for this thread
    const int vchunk = (vd2 >> 3) * 2 + (vg >> 2);
    const int vlane = (vg & 3) * 16 + ((2 * vd2) & 15);

    for (int kt = 0; kt < 32; ++kt) {
        __syncthreads();  // A: prev compute's lK/lVt reads done
        // ---- store staged tiles (lane-linear K write; Vt fragment write) ----
#pragma unroll
        for (int i = 0; i < 2; ++i)
            *reinterpret_cast<uint4*>(&lK[(w * 2 + i) * 512 + l * 8]) = rk[i];
        {
            uint4 cA, cB;
            cA.x = __builtin_amdgcn_perm(rvv[1], rvv[0], 0x05040100);
            cA.y = __builtin_amdgcn_perm(rvv[3], rvv[2], 0x05040100);
            cA.z = __builtin_amdgcn_perm(rvv[5], rvv[4], 0x05040100);
            cA.w = __builtin_amdgcn_perm(rvv[7], rvv[6], 0x05040100);
            cB.x = __builtin_amdgcn_perm(rvv[1], rvv[0], 0x07060302);
            cB.y = __builtin_amdgcn_perm(rvv[3], rvv[2], 0x07060302);
            cB.z = __builtin_amdgcn_perm(rvv[5], rvv[4], 0x07060302);
            cB.w = __builtin_amdgcn_perm(rvv[7], rvv[6], 0x07060302);
            u16* vdst = &lVt[vchunk * 512 + vlane * 8];
            *reinterpret_cast<uint4*>(vdst) = cA;       // Vt row 2*vd2
            *reinterpret_cast<uint4*>(vdst + 8) = cB;   // Vt row 2*vd2+1
        }
        __syncthreads();  // B
        // ---- issue kt+1 loads (in flight during compute) ----
        {
            int ktn = (kt < 31) ? kt + 1 : kt;
            const int sk0n = ktn * 64;
#pragma unroll
            for (int i = 0; i < 2; ++i) {
                int c = w * 2 + i;
                rk[i] = *reinterpret_cast<const uint4*>(
                    kh + headbase + (size_t)(sk0n + (c >> 1) * 16 + c16) * DH +
                    (c & 1) * 32 + kcol);
            }
#pragma unroll
            for (int e = 0; e < 8; ++e)
                rvv[e] = *reinterpret_cast<const unsigned int*>(
                    vh + headbase + (size_t)(sk0n + vg * 8 + e) * DH + vd2 * 2);
            mw_next0 = pm[pmrow0 + ktn];
            mw_next1 = pm[pmrow1 + ktn];
        }

        // ---- S^T = K Q^T : lane holds S^T[sk=ni*16+quad*4+r][q=w*32+g*16+c16]
        f32x4 sAcc[2][4] = {};
        __builtin_amdgcn_s_setprio(1);
#pragma unroll
        for (int ks = 0; ks < 2; ++ks) {
#pragma unroll
            for (int ni = 0; ni < 4; ++ni) {
                bf16x8 kf = *reinterpret_cast<const bf16x8*>(
                    &lK[(ni * 2 + ks) * 512 + l * 8]);
                sAcc[0][ni] = __builtin_amdgcn_mfma_f32_16x16x32_bf16(
                    kf, qf[0][ks], sAcc[0][ni], 0, 0, 0);
                sAcc[1][ni] = __builtin_amdgcn_mfma_f32_16x16x32_bf16(
                    kf, qf[1][ks], sAcc[1][ni], 0, 0, 0);
            }
        }
        __builtin_amdgcn_s_setprio(0);

        // ---- mask + exp2 + packed P store (2 groups x 4 x ds_write_b64) ----
#pragma unroll
        for (int g = 0; g < 2; ++g) {
            unsigned long long mw = g ? mw_cur1 : mw_cur0;
            unsigned long long mq = mw >> (quad * 4);
            unsigned int mlo = (unsigned int)mq, mhi = (unsigned int)(mq >> 32);
            float rs = 0.f;
#pragma unroll
            for (int ni = 0; ni < 4; ++ni) {
                unsigned int half = (ni < 2) ? mlo : mhi;
                unsigned int sh = (ni & 1) * 16;
                unsigned int w0, w1;
                {
                    float p0 = ((half >> (sh + 0)) & 1u) ? EXP2f(sAcc[g][ni][0]) : 0.f;
                    float p1 = ((half >> (sh + 1)) & 1u) ? EXP2f(sAcc[g][ni][1]) : 0.f;
                    float p2 = ((half >> (sh + 2)) & 1u) ? EXP2f(sAcc[g][ni][2]) : 0.f;
                    float p3 = ((half >> (sh + 3)) & 1u) ? EXP2f(sAcc[g][ni][3]) : 0.f;
                    rs += (p0 + p1) + (p2 + p3);
                    w0 = __builtin_amdgcn_perm(__float_as_uint(p1) + 0x8000u,
                                               __float_as_uint(p0) + 0x8000u, 0x07060302);
                    w1 = __builtin_amdgcn_perm(__float_as_uint(p3) + 0x8000u,
                                               __float_as_uint(p2) + 0x8000u, 0x07060302);
                }
                uint2 pv; pv.x = w0; pv.y = w1;
                *reinterpret_cast<uint2*>(
                    &lP[(w * 32 + g * 16 + c16) * 72 + ni * 16 + quad * 4]) = pv;
            }
            if (g == 0) rsumAcc[0] += rs; else rsumAcc[1] += rs;
        }
        mw_cur0 = mw_next0; mw_cur1 = mw_next1;
        // wave-private lP RAW: drain DS queue, no cross-wave barrier needed
        __asm__ volatile("s_waitcnt lgkmcnt(0)" ::: "memory");

        // ---- O += P @ V : vf reads lane-linear; each feeds both q-groups ----
        __builtin_amdgcn_s_setprio(1);
#pragma unroll
        for (int ks = 0; ks < 2; ++ks) {
            bf16x8 pf0 = *reinterpret_cast<const bf16x8*>(
                &lP[(w * 32 + c16) * 72 + ks * 32 + quad * 8]);
            bf16x8 pf1 = *reinterpret_cast<const bf16x8*>(
                &lP[(w * 32 + 16 + c16) * 72 + ks * 32 + quad * 8]);
#pragma unroll
            for (int no = 0; no < 4; ++no) {
                bf16x8 vf = *reinterpret_cast<const bf16x8*>(
                    &lVt[(no * 2 + ks) * 512 + l * 8]);
                oAcc[0][no] = __builtin_amdgcn_mfma_f32_16x16x32_bf16(
                    pf0, vf, oAcc[0][no], 0, 0, 0);
                oAcc[1][no] = __builtin_amdgcn_mfma_f32_16x16x32_bf16(
                    pf1, vf, oAcc[1][no], 0, 0, 0);
            }
        }
        __builtin_amdgcn_s_setprio(0);
    }

    // ---- epilogue: row-sum reduce, normalize, restage O in lP, write ----
    float linv[2][4];
#pragma unroll
    for (int g = 0; g < 2; ++g) {
        float s = (g == 0) ? rsumAcc[0] : rsumAcc[1];
        s += __shfl_xor(s, 16);
        s += __shfl_xor(s, 32);
        float rinv = 1.0f / s;
#pragma unroll
        for (int r = 0; r < 4; ++r)
            linv[g][r] = __shfl(rinv, quad * 4 + r);
    }
#pragma unroll
    for (int g = 0; g < 2; ++g)
#pragma unroll
        for (int no = 0; no < 4; ++no)
#pragma unroll
            for (int r = 0; r < 4; ++r)
                lP[(w * 32 + g * 16 + quad * 4 + r) * 72 + no * 16 + c16] =
                    f2bf_fast(oAcc[g][no][r] * linv[g][r]);
    __syncthreads();
#pragma unroll
    for (int i = 0; i < 4; ++i) {
        int idx = t + i * 256;
        int row = idx >> 3, ch = idx & 7;
        uint4 val = *reinterpret_cast<const uint4*>(&lP[row * 72 + ch * 8]);
        *reinterpret_cast<uint4*>(
            ao + ((size_t)b * SS + sq0 + row) * D_MODEL + h * DH + ch * 8) = val;
    }
}

extern "C" void kernel_launch(void* const* d_in, const int* in_sizes, int n_in,
                              void* d_out, int out_size, void* d_ws, size_t ws_size,
                              hipStream_t stream)
{
    const float* q    = (const float*)d_in[0];
    const float* k    = (const float*)d_in[1];
    const float* v    = (const float*)d_in[2];
    const int*   mask = (const int*)d_in[3];
    const float* Wq   = (const float*)d_in[4];
    const float* bq   = (const float*)d_in[5];
    const float* Wk   = (const float*)d_in[6];
    const float* bk   = (const float*)d_in[7];
    const float* Wv   = (const float*)d_in[8];
    const float* bv   = (const float*)d_in[9];
    const float* Wo   = (const float*)d_in[10];
    const float* bo   = (const float*)d_in[11];

    const size_t T4M = (size_t)BB * SS * D_MODEL;  // 4,194,304 elems
    u16* qh = (u16*)d_ws;                          // [B][NH][S][DH] bf16 (Q pre-scaled)
    u16* kh = qh + T4M;
    u16* vh = kh + T4M;
    u16* ao = vh + T4M;                            // [B][S][D] bf16
    u16* cW = ao + T4M;                            // 4 x 1M bf16 (Wq,Wk,Wv,Wo)
    u16* qb = cW + 4 * (size_t)D_MODEL * D_MODEL;  // q,k,v as bf16 (3 x 4M)
    unsigned long long* pm = (unsigned long long*)(qb + 3 * T4M);
    float* out = (float*)d_out;

    prep_kernel<<<9216, 256, 0, stream>>>(Wq, Wk, Wv, Wo, cW, q, k, v, qb, mask, pm);
    qkv_kernel<<<dim3(32, 8, 3), 256, 0, stream>>>(qb, cW, bq, bk, bv, qh, kh, vh);
    attn_kernel<<<dim3(16, NH, BB), 256, 0, stream>>>(qh, kh, vh, pm, ao);
    oproj_kernel<<<dim3(32, 8), 256, 0, stream>>>(ao, cW + 3 * (size_t)D_MODEL * D_MODEL, bo, out);
}

// Round 14
// 299.221 us; speedup vs baseline: 1.0394x; 1.0110x over previous
//
#include <hip/hip_runtime.h>

typedef unsigned short u16;
typedef __bf16 bf16x8 __attribute__((ext_vector_type(8)));
typedef float f32x4 __attribute__((ext_vector_type(4)));

#define D_MODEL 1024
#define NH 16
#define DH 64
#define BB 2
#define SS 2048

#if __has_builtin(__builtin_amdgcn_exp2f)
#define EXP2f(x) __builtin_amdgcn_exp2f(x)
#else
#define EXP2f(x) exp2f(x)
#endif

__device__ __forceinline__ u16 f2bf_fast(float f) {
    union { float f; unsigned int u; } v; v.f = f;
    return (u16)((v.u + 0x8000u) >> 16);
}
// single-op packed fp32x2 -> bf16x2 (RTNE), low=lo high=hi (T12 recipe)
__device__ __forceinline__ unsigned int cvtpk_bf16(float lo, float hi) {
    unsigned int r;
    asm("v_cvt_pk_bf16_f32 %0, %1, %2" : "=v"(r) : "v"(lo), "v"(hi));
    return r;
}
// pack 8 fp32 -> 8 bf16 (half-up): 8 add + 4 perm
__device__ __forceinline__ uint4 pack8(const float4& a, const float4& b) {
    unsigned int a0 = __float_as_uint(a.x) + 0x8000u, a1 = __float_as_uint(a.y) + 0x8000u;
    unsigned int a2 = __float_as_uint(a.z) + 0x8000u, a3 = __float_as_uint(a.w) + 0x8000u;
    unsigned int b0 = __float_as_uint(b.x) + 0x8000u, b1 = __float_as_uint(b.y) + 0x8000u;
    unsigned int b2 = __float_as_uint(b.z) + 0x8000u, b3 = __float_as_uint(b.w) + 0x8000u;
    uint4 r;
    r.x = __builtin_amdgcn_perm(a1, a0, 0x07060302);
    r.y = __builtin_amdgcn_perm(a3, a2, 0x07060302);
    r.z = __builtin_amdgcn_perm(b1, b0, 0x07060302);
    r.w = __builtin_amdgcn_perm(b3, b2, 0x07060302);
    return r;
}

__device__ __forceinline__ void gld16(const void* g, void* l) {
    __builtin_amdgcn_global_load_lds(
        (const __attribute__((address_space(1))) unsigned int*)g,
        (__attribute__((address_space(3))) unsigned int*)l, 16, 0, 0);
}

// Fused prep:
//   blocks [0,2048)    : Wq/Wk/Wv/Wo fp32 -> cW bf16 (512 blocks per weight)
//   blocks [2048,8192) : q,k,v fp32 -> qb bf16 (2048 blocks per tensor)
//   blocks [8192,9216) : mask int32 -> bitmask pm[B*S][S/64]
__global__ __launch_bounds__(256) void prep_kernel(
    const float* __restrict__ Wq, const float* __restrict__ Wk,
    const float* __restrict__ Wv, const float* __restrict__ Wo, u16* __restrict__ cW,
    const float* __restrict__ q, const float* __restrict__ k,
    const float* __restrict__ v, u16* __restrict__ qb,
    const int* __restrict__ mask, unsigned long long* __restrict__ pm)
{
    int bid = blockIdx.x;
    if (bid < 2048) {
        int z = bid >> 9, x = bid & 511;
        const float* src = (z == 0) ? Wq : (z == 1) ? Wk : (z == 2) ? Wv : Wo;
        u16* dst = cW + (size_t)z * D_MODEL * D_MODEL;
        size_t base = ((size_t)x * 256 + threadIdx.x) * 8;
        float4 a = *reinterpret_cast<const float4*>(src + base);
        float4 b = *reinterpret_cast<const float4*>(src + base + 4);
        *reinterpret_cast<uint4*>(dst + base) = pack8(a, b);
    } else if (bid < 8192) {
        int x = bid - 2048;
        int z = x >> 11, xx = x & 2047;
        const float* src = (z == 0) ? q : (z == 1) ? k : v;
        u16* dst = qb + (size_t)z * BB * SS * D_MODEL;
        size_t base = ((size_t)xx * 256 + threadIdx.x) * 8;
        float4 a = *reinterpret_cast<const float4*>(src + base);
        float4 b = *reinterpret_cast<const float4*>(src + base + 4);
        *reinterpret_cast<uint4*>(dst + base) = pack8(a, b);
    } else {
        int x = bid - 8192;
        int gw = (x * 256 + threadIdx.x) >> 6;   // 0..4095
        int l = threadIdx.x & 63;
#pragma unroll 4
        for (int i = 0; i < 32; ++i) {
            int widx = gw * 32 + i;
            int m = mask[(size_t)widx * 64 + l];
            unsigned long long bits = __ballot(m != 0);
            if (l == 0) pm[widx] = bits;
        }
    }
}

// m97-structure NT GEMM, all-bf16 operands (Round-2 proven): gld16 width-16
// staging, stride-64 LDS, 2-barrier K-loop.
// C[m,n] = (sum_k A[m,k]*W[n,k] + bias[n]) * oscale.
// QKV=1: epilogue restages tile in LDS -> coalesced [b,h,s,dh] bf16 writes.
// QKV=0: direct fp32 scatter (64-B chunks).
template<int OF32, int QKV>
__device__ void gemm_bb(const u16* __restrict__ A, const u16* __restrict__ W,
                        const float* __restrict__ bias, void* outp, float oscale)
{
    __shared__ __align__(16) u16 smem[128 * 144];   // staging: 2x 128*64; restage: 128*136
    u16* lA = smem;
    u16* lW = smem + 128 * 64;
    const int t = threadIdx.x, w = t >> 6, l = t & 63;
    const int blockM = blockIdx.x * 128, blockN = blockIdx.y * 128;
    const int lrow = l >> 3, lcol = (l & 7) * 8;
    const int quad = l >> 4, c16 = l & 15;

    f32x4 acc[4][4] = {};

    for (int kt = 0; kt < 16; ++kt) {
        __syncthreads();
#pragma unroll
        for (int i = 0; i < 4; ++i) {
            int c = w * 4 + i;
            int row = c * 8 + lrow;
            gld16(A + (size_t)(blockM + row) * 1024 + kt * 64 + lcol, &lA[c * 512]);
            gld16(W + (size_t)(blockN + row) * 1024 + kt * 64 + lcol, &lW[c * 512]);
        }
        __syncthreads();
#pragma unroll
        for (int ks = 0; ks < 2; ++ks) {
            bf16x8 af[4], bfr[4];
#pragma unroll
            for (int mi = 0; mi < 4; ++mi)
                af[mi] = *reinterpret_cast<const bf16x8*>(
                    &lA[((w & 1) * 64 + mi * 16 + c16) * 64 + ks * 32 + quad * 8]);
#pragma unroll
            for (int ni = 0; ni < 4; ++ni)
                bfr[ni] = *reinterpret_cast<const bf16x8*>(
                    &lW[((w >> 1) * 64 + ni * 16 + c16) * 64 + ks * 32 + quad * 8]);
#pragma unroll
            for (int mi = 0; mi < 4; ++mi)
#pragma unroll
                for (int ni = 0; ni < 4; ++ni)
                    acc[mi][ni] = __builtin_amdgcn_mfma_f32_16x16x32_bf16(
                        af[mi], bfr[ni], acc[mi][ni], 0, 0, 0);
        }
    }

    if (QKV) {
        // restage through LDS (stride 136) -> full-line [b,h,s,dh] writes
        __syncthreads();
        const int m_base = (w & 1) * 64, n_base = (w >> 1) * 64;
#pragma unroll
        for (int ni = 0; ni < 4; ++ni) {
            int n_local = n_base + ni * 16 + c16;
            float bv = bias[blockN + n_local];
#pragma unroll
            for (int mi = 0; mi < 4; ++mi)
#pragma unroll
                for (int r = 0; r < 4; ++r) {
                    int m_local = m_base + mi * 16 + quad * 4 + r;
                    smem[m_local * 136 + n_local] =
                        f2bf_fast((acc[mi][ni][r] + bv) * oscale);
                }
        }
        __syncthreads();
        const int bb = blockM >> 11, s_base = blockM & 2047;
        u16* outb = (u16*)outp;
#pragma unroll
        for (int i = 0; i < 8; ++i) {
            int idx = t + i * 256;
            int mrow = idx >> 4, ch = idx & 15;
            uint4 val = *reinterpret_cast<const uint4*>(&smem[mrow * 136 + ch * 8]);
            int gn = blockN + ch * 8;
            int hh = gn >> 6, dh = gn & 63;
            *reinterpret_cast<uint4*>(
                outb + (((size_t)(bb * NH + hh)) * SS + s_base + mrow) * DH + dh) = val;
        }
        return;
    }

    const int m0 = blockM + (w & 1) * 64, n0 = blockN + (w >> 1) * 64;
#pragma unroll
    for (int ni = 0; ni < 4; ++ni) {
        int n = n0 + ni * 16 + c16;
        float bv = bias[n];
#pragma unroll
        for (int mi = 0; mi < 4; ++mi) {
#pragma unroll
            for (int r = 0; r < 4; ++r) {
                int m = m0 + mi * 16 + quad * 4 + r;
                float val = (acc[mi][ni][r] + bv) * oscale;
                ((float*)outp)[(size_t)m * 1024 + n] = val;
            }
        }
    }
}

__global__ __launch_bounds__(256) void qkv_kernel(
    const u16* __restrict__ qb, const u16* __restrict__ cW,
    const float* __restrict__ bq, const float* __restrict__ bk, const float* __restrict__ bv,
    u16* __restrict__ qh, u16* __restrict__ kh, u16* __restrict__ vh)
{
    int z = blockIdx.z;
    const u16* A = qb + (size_t)z * BB * SS * D_MODEL;
    const u16* W = cW + (size_t)z * D_MODEL * D_MODEL;
    const float* bias = (z == 0) ? bq : (z == 1) ? bk : bv;
    u16* out = (z == 0) ? qh : (z == 1) ? kh : vh;
    // fold 1/sqrt(dh) AND log2(e) into Q so softmax uses raw v_exp_f32 (exp2)
    float oscale = (z == 0) ? 0.18033688011112042f : 1.0f;
    gemm_bb<0, 1>(A, W, bias, out, oscale);
}

__global__ __launch_bounds__(256) void oproj_kernel(
    const u16* __restrict__ A, const u16* __restrict__ cWo,
    const float* __restrict__ bo, float* __restrict__ out)
{
    gemm_bb<1, 0>(A, cWo, bo, out, 1.0f);
}

// Flash attention v4: QBLK=128, 4 waves x 32 q-rows, KVBLK=64.
// K/Vt fragment-linear (R10: conflicts halved, verified) and now
// DOUBLE-BUFFERED with a SINGLE barrier per kt iteration:
//   kt: write staged regs -> buf[kt&1]; barrier; issue kt+1 loads; compute.
// Safety: buf[kt&1] was last read at kt-2; barrier(kt-1) separates that read
// from this write (barriers release all-or-none). Key mechanism vs R10: NO
// barrier ever has pending global loads -> the forced vmcnt(0) drain at
// barrier-A (old 2-barrier scheme) is gone; 64 -> 32 barriers.
// Softmax P-pack via v_cvt_pk_bf16_f32 (1 op / 2 vals, T12).
// LDS = 16K(lK dbuf) + 16K(lVt dbuf) + 18K(lP) = 50 KB; grid-limited 2/CU.
__global__ __launch_bounds__(256, 2) void attn_kernel(
    const u16* __restrict__ qh, const u16* __restrict__ kh, const u16* __restrict__ vh,
    const unsigned long long* __restrict__ pm, u16* __restrict__ ao)
{
    __shared__ __align__(16) u16 lK[2][8 * 512];    // fragment-linear, dbuf
    __shared__ __align__(16) u16 lVt[2][8 * 512];   // fragment-linear, dbuf
    __shared__ __align__(16) u16 lP[128 * 72];      // Q stage / P tile / O restage

    const int t = threadIdx.x, w = t >> 6, l = t & 63;
    const int qt = blockIdx.x, h = blockIdx.y, b = blockIdx.z;
    const int sq0 = qt * 128;
    const size_t headbase = ((size_t)(b * NH + h)) * SS * DH;
    const int quad = l >> 4, c16 = l & 15;
    const int lrow = l >> 3, lcol = (l & 7) * 8;
    const int vd2 = t & 31, vg = t >> 5;

    // ---- stage Q once (pre-scaled by 0.125*log2e at projection) ----
    // wave w owns lP rows [w*32, w*32+32): wave-private, no barrier needed
#pragma unroll
    for (int i = 0; i < 4; ++i) {
        int row = (w * 4 + i) * 8 + lrow;
        uint4 rq = *reinterpret_cast<const uint4*>(
            qh + headbase + (size_t)(sq0 + row) * DH + lcol);
        *reinterpret_cast<uint4*>(&lP[row * 72 + lcol]) = rq;
    }
    __asm__ volatile("s_waitcnt lgkmcnt(0)" ::: "memory");
    bf16x8 qf[2][2];
#pragma unroll
    for (int g = 0; g < 2; ++g)
#pragma unroll
        for (int ks = 0; ks < 2; ++ks)
            qf[g][ks] = *reinterpret_cast<const bf16x8*>(
                &lP[(w * 32 + g * 16 + c16) * 72 + ks * 32 + quad * 8]);

    f32x4 oAcc[2][4] = {};
    float rsumAcc[2] = {0.f, 0.f};
    const size_t pmrow0 = ((size_t)b * SS + sq0 + w * 32 + c16) * 32;
    const size_t pmrow1 = pmrow0 + 16 * 32;

    // K fragment-mapped global coords: chunk c = w*2+i, lane l ->
    // row (c>>1)*16 + c16, cols (c&1)*32 + quad*8 (u16 units)
    const int kcol = quad * 8;

    // prime kt=0 loads
    uint4 rk[2];
    unsigned int rvv[8];
    unsigned long long mw_cur0, mw_cur1, mw_next0, mw_next1;
#pragma unroll
    for (int i = 0; i < 2; ++i) {
        int c = w * 2 + i;
        rk[i] = *reinterpret_cast<const uint4*>(
            kh + headbase + (size_t)((c >> 1) * 16 + c16) * DH + (c & 1) * 32 + kcol);
    }
#pragma unroll
    for (int e = 0; e < 8; ++e)
        rvv[e] = *reinterpret_cast<const unsigned int*>(
            vh + headbase + (size_t)(vg * 8 + e) * DH + vd2 * 2);
    mw_cur0 = pm[pmrow0 + 0];
    mw_cur1 = pm[pmrow1 + 0];

    // Vt fragment write coords for this thread
    const int vchunk = (vd2 >> 3) * 2 + (vg >> 2);
    const int vlane = (vg & 3) * 16 + ((2 * vd2) & 15);

    for (int kt = 0; kt < 32; ++kt) {
        const int cur = kt & 1;
        // ---- store staged tiles into buf[cur] (no pre-barrier needed) ----
#pragma unroll
        for (int i = 0; i < 2; ++i)
            *reinterpret_cast<uint4*>(&lK[cur][(w * 2 + i) * 512 + l * 8]) = rk[i];
        {
            uint4 cA, cB;
            cA.x = __builtin_amdgcn_perm(rvv[1], rvv[0], 0x05040100);
            cA.y = __builtin_amdgcn_perm(rvv[3], rvv[2], 0x05040100);
            cA.z = __builtin_amdgcn_perm(rvv[5], rvv[4], 0x05040100);
            cA.w = __builtin_amdgcn_perm(rvv[7], rvv[6], 0x05040100);
            cB.x = __builtin_amdgcn_perm(rvv[1], rvv[0], 0x07060302);
            cB.y = __builtin_amdgcn_perm(rvv[3], rvv[2], 0x07060302);
            cB.z = __builtin_amdgcn_perm(rvv[5], rvv[4], 0x07060302);
            cB.w = __builtin_amdgcn_perm(rvv[7], rvv[6], 0x07060302);
            u16* vdst = &lVt[cur][vchunk * 512 + vlane * 8];
            *reinterpret_cast<uint4*>(vdst) = cA;       // Vt row 2*vd2
            *reinterpret_cast<uint4*>(vdst + 8) = cB;   // Vt row 2*vd2+1
        }
        __syncthreads();   // single barrier: buf[cur] visible; no global loads pending
        // ---- issue kt+1 loads (in flight through next iteration's store) ----
        {
            int ktn = (kt < 31) ? kt + 1 : kt;
            const int sk0n = ktn * 64;
#pragma unroll
            for (int i = 0; i < 2; ++i) {
                int c = w * 2 + i;
                rk[i] = *reinterpret_cast<const uint4*>(
                    kh + headbase + (size_t)(sk0n + (c >> 1) * 16 + c16) * DH +
                    (c & 1) * 32 + kcol);
            }
#pragma unroll
            for (int e = 0; e < 8; ++e)
                rvv[e] = *reinterpret_cast<const unsigned int*>(
                    vh + headbase + (size_t)(sk0n + vg * 8 + e) * DH + vd2 * 2);
            mw_next0 = pm[pmrow0 + ktn];
            mw_next1 = pm[pmrow1 + ktn];
        }

        // ---- S^T = K Q^T : lane holds S^T[sk=ni*16+quad*4+r][q=w*32+g*16+c16]
        f32x4 sAcc[2][4] = {};
        __builtin_amdgcn_s_setprio(1);
#pragma unroll
        for (int ks = 0; ks < 2; ++ks) {
#pragma unroll
            for (int ni = 0; ni < 4; ++ni) {
                bf16x8 kf = *reinterpret_cast<const bf16x8*>(
                    &lK[cur][(ni * 2 + ks) * 512 + l * 8]);
                sAcc[0][ni] = __builtin_amdgcn_mfma_f32_16x16x32_bf16(
                    kf, qf[0][ks], sAcc[0][ni], 0, 0, 0);
                sAcc[1][ni] = __builtin_amdgcn_mfma_f32_16x16x32_bf16(
                    kf, qf[1][ks], sAcc[1][ni], 0, 0, 0);
            }
        }
        __builtin_amdgcn_s_setprio(0);

        // ---- mask + exp2 + cvt_pk P store (2 groups x 4 x ds_write_b64) ----
#pragma unroll
        for (int g = 0; g < 2; ++g) {
            unsigned long long mw = g ? mw_cur1 : mw_cur0;
            unsigned long long mq = mw >> (quad * 4);
            unsigned int mlo = (unsigned int)mq, mhi = (unsigned int)(mq >> 32);
            float rs = 0.f;
#pragma unroll
            for (int ni = 0; ni < 4; ++ni) {
                unsigned int half = (ni < 2) ? mlo : mhi;
                unsigned int sh = (ni & 1) * 16;
                float p0 = ((half >> (sh + 0)) & 1u) ? EXP2f(sAcc[g][ni][0]) : 0.f;
                float p1 = ((half >> (sh + 1)) & 1u) ? EXP2f(sAcc[g][ni][1]) : 0.f;
                float p2 = ((half >> (sh + 2)) & 1u) ? EXP2f(sAcc[g][ni][2]) : 0.f;
                float p3 = ((half >> (sh + 3)) & 1u) ? EXP2f(sAcc[g][ni][3]) : 0.f;
                rs += (p0 + p1) + (p2 + p3);
                uint2 pv;
                pv.x = cvtpk_bf16(p0, p1);
                pv.y = cvtpk_bf16(p2, p3);
                *reinterpret_cast<uint2*>(
                    &lP[(w * 32 + g * 16 + c16) * 72 + ni * 16 + quad * 4]) = pv;
            }
            if (g == 0) rsumAcc[0] += rs; else rsumAcc[1] += rs;
        }
        mw_cur0 = mw_next0; mw_cur1 = mw_next1;
        // wave-private lP RAW: drain DS queue, no cross-wave barrier needed
        __asm__ volatile("s_waitcnt lgkmcnt(0)" ::: "memory");

        // ---- O += P @ V : vf reads lane-linear; each feeds both q-groups ----
        __builtin_amdgcn_s_setprio(1);
#pragma unroll
        for (int ks = 0; ks < 2; ++ks) {
            bf16x8 pf0 = *reinterpret_cast<const bf16x8*>(
                &lP[(w * 32 + c16) * 72 + ks * 32 + quad * 8]);
            bf16x8 pf1 = *reinterpret_cast<const bf16x8*>(
                &lP[(w * 32 + 16 + c16) * 72 + ks * 32 + quad * 8]);
#pragma unroll
            for (int no = 0; no < 4; ++no) {
                bf16x8 vf = *reinterpret_cast<const bf16x8*>(
                    &lVt[cur][(no * 2 + ks) * 512 + l * 8]);
                oAcc[0][no] = __builtin_amdgcn_mfma_f32_16x16x32_bf16(
                    pf0, vf, oAcc[0][no], 0, 0, 0);
                oAcc[1][no] = __builtin_amdgcn_mfma_f32_16x16x32_bf16(
                    pf1, vf, oAcc[1][no], 0, 0, 0);
            }
        }
        __builtin_amdgcn_s_setprio(0);
    }

    // ---- epilogue: row-sum reduce, normalize, restage O in lP, write ----
    float linv[2][4];
#pragma unroll
    for (int g = 0; g < 2; ++g) {
        float s = (g == 0) ? rsumAcc[0] : rsumAcc[1];
        s += __shfl_xor(s, 16);
        s += __shfl_xor(s, 32);
        float rinv = 1.0f / s;
#pragma unroll
        for (int r = 0; r < 4; ++r)
            linv[g][r] = __shfl(rinv, quad * 4 + r);
    }
    // O writes hit wave-private lP rows; PV's pf reads already completed
#pragma unroll
    for (int g = 0; g < 2; ++g)
#pragma unroll
        for (int no = 0; no < 4; ++no)
#pragma unroll
            for (int r = 0; r < 4; ++r)
                lP[(w * 32 + g * 16 + quad * 4 + r) * 72 + no * 16 + c16] =
                    f2bf_fast(oAcc[g][no][r] * linv[g][r]);
    __syncthreads();
#pragma unroll
    for (int i = 0; i < 4; ++i) {
        int idx = t + i * 256;
        int row = idx >> 3, ch = idx & 7;
        uint4 val = *reinterpret_cast<const uint4*>(&lP[row * 72 + ch * 8]);
        *reinterpret_cast<uint4*>(
            ao + ((size_t)b * SS + sq0 + row) * D_MODEL + h * DH + ch * 8) = val;
    }
}

extern "C" void kernel_launch(void* const* d_in, const int* in_sizes, int n_in,
                              void* d_out, int out_size, void* d_ws, size_t ws_size,
                              hipStream_t stream)
{
    const float* q    = (const float*)d_in[0];
    const float* k    = (const float*)d_in[1];
    const float* v    = (const float*)d_in[2];
    const int*   mask = (const int*)d_in[3];
    const float* Wq   = (const float*)d_in[4];
    const float* bq   = (const float*)d_in[5];
    const float* Wk   = (const float*)d_in[6];
    const float* bk   = (const float*)d_in[7];
    const float* Wv   = (const float*)d_in[8];
    const float* bv   = (const float*)d_in[9];
    const float* Wo   = (const float*)d_in[10];
    const float* bo   = (const float*)d_in[11];

    const size_t T4M = (size_t)BB * SS * D_MODEL;  // 4,194,304 elems
    u16* qh = (u16*)d_ws;                          // [B][NH][S][DH] bf16 (Q pre-scaled)
    u16* kh = qh + T4M;
    u16* vh = kh + T4M;
    u16* ao = vh + T4M;                            // [B][S][D] bf16
    u16* cW = ao + T4M;                            // 4 x 1M bf16 (Wq,Wk,Wv,Wo)
    u16* qb = cW + 4 * (size_t)D_MODEL * D_MODEL;  // q,k,v as bf16 (3 x 4M)
    unsigned long long* pm = (unsigned long long*)(qb + 3 * T4M);
    float* out = (float*)d_out;

    prep_kernel<<<9216, 256, 0, stream>>>(Wq, Wk, Wv, Wo, cW, q, k, v, qb, mask, pm);
    qkv_kernel<<<dim3(32, 8, 3), 256, 0, stream>>>(qb, cW, bq, bk, bv, qh, kh, vh);
    attn_kernel<<<dim3(16, NH, BB), 256, 0, stream>>>(qh, kh, vh, pm, ao);
    oproj_kernel<<<dim3(32, 8), 256, 0, stream>>>(ao, cW + 3 * (size_t)D_MODEL * D_MODEL, bo, out);
}

// Round 15
// 295.420 us; speedup vs baseline: 1.0528x; 1.0129x over previous
//
#include <hip/hip_runtime.h>

typedef unsigned short u16;
typedef __bf16 bf16x8 __attribute__((ext_vector_type(8)));
typedef float f32x4 __attribute__((ext_vector_type(4)));

#define D_MODEL 1024
#define NH 16
#define DH 64
#define BB 2
#define SS 2048

#if __has_builtin(__builtin_amdgcn_exp2f)
#define EXP2f(x) __builtin_amdgcn_exp2f(x)
#else
#define EXP2f(x) exp2f(x)
#endif

__device__ __forceinline__ u16 f2bf_fast(float f) {
    union { float f; unsigned int u; } v; v.f = f;
    return (u16)((v.u + 0x8000u) >> 16);
}
// single-op packed fp32x2 -> bf16x2 (RTNE), low=lo high=hi (T12 recipe)
__device__ __forceinline__ unsigned int cvtpk_bf16(float lo, float hi) {
    unsigned int r;
    asm("v_cvt_pk_bf16_f32 %0, %1, %2" : "=v"(r) : "v"(lo), "v"(hi));
    return r;
}
// pack 8 fp32 -> 8 bf16 (half-up): 8 add + 4 perm
__device__ __forceinline__ uint4 pack8(const float4& a, const float4& b) {
    unsigned int a0 = __float_as_uint(a.x) + 0x8000u, a1 = __float_as_uint(a.y) + 0x8000u;
    unsigned int a2 = __float_as_uint(a.z) + 0x8000u, a3 = __float_as_uint(a.w) + 0x8000u;
    unsigned int b0 = __float_as_uint(b.x) + 0x8000u, b1 = __float_as_uint(b.y) + 0x8000u;
    unsigned int b2 = __float_as_uint(b.z) + 0x8000u, b3 = __float_as_uint(b.w) + 0x8000u;
    uint4 r;
    r.x = __builtin_amdgcn_perm(a1, a0, 0x07060302);
    r.y = __builtin_amdgcn_perm(a3, a2, 0x07060302);
    r.z = __builtin_amdgcn_perm(b1, b0, 0x07060302);
    r.w = __builtin_amdgcn_perm(b3, b2, 0x07060302);
    return r;
}

__device__ __forceinline__ void gld16(const void* g, void* l) {
    __builtin_amdgcn_global_load_lds(
        (const __attribute__((address_space(1))) unsigned int*)g,
        (__attribute__((address_space(3))) unsigned int*)l, 16, 0, 0);
}

// Fused prep:
//   blocks [0,2048)    : Wq/Wk/Wv/Wo fp32 -> cW bf16 (512 blocks per weight)
//   blocks [2048,8192) : q,k,v fp32 -> qb bf16 (2048 blocks per tensor)
//   blocks [8192,9216) : mask int32 -> bitmask pm[B*S][S/64]
__global__ __launch_bounds__(256) void prep_kernel(
    const float* __restrict__ Wq, const float* __restrict__ Wk,
    const float* __restrict__ Wv, const float* __restrict__ Wo, u16* __restrict__ cW,
    const float* __restrict__ q, const float* __restrict__ k,
    const float* __restrict__ v, u16* __restrict__ qb,
    const int* __restrict__ mask, unsigned long long* __restrict__ pm)
{
    int bid = blockIdx.x;
    if (bid < 2048) {
        int z = bid >> 9, x = bid & 511;
        const float* src = (z == 0) ? Wq : (z == 1) ? Wk : (z == 2) ? Wv : Wo;
        u16* dst = cW + (size_t)z * D_MODEL * D_MODEL;
        size_t base = ((size_t)x * 256 + threadIdx.x) * 8;
        float4 a = *reinterpret_cast<const float4*>(src + base);
        float4 b = *reinterpret_cast<const float4*>(src + base + 4);
        *reinterpret_cast<uint4*>(dst + base) = pack8(a, b);
    } else if (bid < 8192) {
        int x = bid - 2048;
        int z = x >> 11, xx = x & 2047;
        const float* src = (z == 0) ? q : (z == 1) ? k : v;
        u16* dst = qb + (size_t)z * BB * SS * D_MODEL;
        size_t base = ((size_t)xx * 256 + threadIdx.x) * 8;
        float4 a = *reinterpret_cast<const float4*>(src + base);
        float4 b = *reinterpret_cast<const float4*>(src + base + 4);
        *reinterpret_cast<uint4*>(dst + base) = pack8(a, b);
    } else {
        int x = bid - 8192;
        int gw = (x * 256 + threadIdx.x) >> 6;   // 0..4095
        int l = threadIdx.x & 63;
#pragma unroll 4
        for (int i = 0; i < 32; ++i) {
            int widx = gw * 32 + i;
            int m = mask[(size_t)widx * 64 + l];
            unsigned long long bits = __ballot(m != 0);
            if (l == 0) pm[widx] = bits;
        }
    }
}

// m97-structure NT GEMM, all-bf16 operands (Round-2 proven): gld16 width-16
// staging, stride-64 LDS, 2-barrier K-loop. 128x128 tile, 4 waves 2x2.
// C[m,n] = (sum_k A[m,k]*W[n,k] + bias[n]) * oscale.
// Epilogue restages tile in LDS -> coalesced [b,h,s,dh] bf16 writes.
__device__ void gemm_qkv(const u16* __restrict__ A, const u16* __restrict__ W,
                         const float* __restrict__ bias, u16* __restrict__ outp,
                         float oscale)
{
    __shared__ __align__(16) u16 smem[128 * 144];   // staging: 2x 128*64; restage: 128*136
    u16* lA = smem;
    u16* lW = smem + 128 * 64;
    const int t = threadIdx.x, w = t >> 6, l = t & 63;
    const int blockM = blockIdx.x * 128, blockN = blockIdx.y * 128;
    const int lrow = l >> 3, lcol = (l & 7) * 8;
    const int quad = l >> 4, c16 = l & 15;

    f32x4 acc[4][4] = {};

    for (int kt = 0; kt < 16; ++kt) {
        __syncthreads();
#pragma unroll
        for (int i = 0; i < 4; ++i) {
            int c = w * 4 + i;
            int row = c * 8 + lrow;
            gld16(A + (size_t)(blockM + row) * 1024 + kt * 64 + lcol, &lA[c * 512]);
            gld16(W + (size_t)(blockN + row) * 1024 + kt * 64 + lcol, &lW[c * 512]);
        }
        __syncthreads();
#pragma unroll
        for (int ks = 0; ks < 2; ++ks) {
            bf16x8 af[4], bfr[4];
#pragma unroll
            for (int mi = 0; mi < 4; ++mi)
                af[mi] = *reinterpret_cast<const bf16x8*>(
                    &lA[((w & 1) * 64 + mi * 16 + c16) * 64 + ks * 32 + quad * 8]);
#pragma unroll
            for (int ni = 0; ni < 4; ++ni)
                bfr[ni] = *reinterpret_cast<const bf16x8*>(
                    &lW[((w >> 1) * 64 + ni * 16 + c16) * 64 + ks * 32 + quad * 8]);
#pragma unroll
            for (int mi = 0; mi < 4; ++mi)
#pragma unroll
                for (int ni = 0; ni < 4; ++ni)
                    acc[mi][ni] = __builtin_amdgcn_mfma_f32_16x16x32_bf16(
                        af[mi], bfr[ni], acc[mi][ni], 0, 0, 0);
        }
    }

    // restage through LDS (stride 136) -> full-line [b,h,s,dh] writes
    __syncthreads();
    const int m_base = (w & 1) * 64, n_base = (w >> 1) * 64;
#pragma unroll
    for (int ni = 0; ni < 4; ++ni) {
        int n_local = n_base + ni * 16 + c16;
        float bv = bias[blockN + n_local];
#pragma unroll
        for (int mi = 0; mi < 4; ++mi)
#pragma unroll
            for (int r = 0; r < 4; ++r) {
                int m_local = m_base + mi * 16 + quad * 4 + r;
                smem[m_local * 136 + n_local] =
                    f2bf_fast((acc[mi][ni][r] + bv) * oscale);
            }
    }
    __syncthreads();
    const int bb = blockM >> 11, s_base = blockM & 2047;
#pragma unroll
    for (int i = 0; i < 8; ++i) {
        int idx = t + i * 256;
        int mrow = idx >> 4, ch = idx & 15;
        uint4 val = *reinterpret_cast<const uint4*>(&smem[mrow * 136 + ch * 8]);
        int gn = blockN + ch * 8;
        int hh = gn >> 6, dh = gn & 63;
        *reinterpret_cast<uint4*>(
            outp + (((size_t)(bb * NH + hh)) * SS + s_base + mrow) * DH + dh) = val;
    }
}

__global__ __launch_bounds__(256) void qkv_kernel(
    const u16* __restrict__ qb, const u16* __restrict__ cW,
    const float* __restrict__ bq, const float* __restrict__ bk, const float* __restrict__ bv,
    u16* __restrict__ qh, u16* __restrict__ kh, u16* __restrict__ vh)
{
    int z = blockIdx.z;
    const u16* A = qb + (size_t)z * BB * SS * D_MODEL;
    const u16* W = cW + (size_t)z * D_MODEL * D_MODEL;
    const float* bias = (z == 0) ? bq : (z == 1) ? bk : bv;
    u16* out = (z == 0) ? qh : (z == 1) ? kh : vh;
    // fold 1/sqrt(dh) AND log2(e) into Q so softmax uses raw v_exp_f32 (exp2)
    float oscale = (z == 0) ? 0.18033688011112042f : 1.0f;
    gemm_qkv(A, W, bias, out, oscale);
}

// oproj GEMM v2: 128x64 tile -> grid (32,16) = 512 blocks = 2 blocks/CU
// (was 128x128 -> 256 blocks = 1/CU = 1 wave/SIMD: zero cross-block latency
// hiding for gld16 staging). 4 waves 2x2 over (128M, 64N): wave owns 64x32,
// acc[4][2], 8 MFMA/ks. lW shrinks to 64x64 (8KB); LDS 24KB.
__global__ __launch_bounds__(256) void oproj_kernel(
    const u16* __restrict__ A, const u16* __restrict__ W,
    const float* __restrict__ bias, float* __restrict__ outp)
{
    __shared__ __align__(16) u16 lA[128 * 64];
    __shared__ __align__(16) u16 lW[64 * 64];
    const int t = threadIdx.x, w = t >> 6, l = t & 63;
    const int blockM = blockIdx.x * 128, blockN = blockIdx.y * 64;
    const int lrow = l >> 3, lcol = (l & 7) * 8;
    const int quad = l >> 4, c16 = l & 15;

    f32x4 acc[4][2] = {};

    for (int kt = 0; kt < 16; ++kt) {
        __syncthreads();
#pragma unroll
        for (int i = 0; i < 4; ++i) {
            int c = w * 4 + i;                       // 16 chunks: A 128 rows
            int row = c * 8 + lrow;
            gld16(A + (size_t)(blockM + row) * 1024 + kt * 64 + lcol, &lA[c * 512]);
        }
#pragma unroll
        for (int i = 0; i < 2; ++i) {
            int c = w * 2 + i;                       // 8 chunks: W 64 rows
            int row = c * 8 + lrow;
            gld16(W + (size_t)(blockN + row) * 1024 + kt * 64 + lcol, &lW[c * 512]);
        }
        __syncthreads();
#pragma unroll
        for (int ks = 0; ks < 2; ++ks) {
            bf16x8 af[4], bfr[2];
#pragma unroll
            for (int mi = 0; mi < 4; ++mi)
                af[mi] = *reinterpret_cast<const bf16x8*>(
                    &lA[((w & 1) * 64 + mi * 16 + c16) * 64 + ks * 32 + quad * 8]);
#pragma unroll
            for (int ni = 0; ni < 2; ++ni)
                bfr[ni] = *reinterpret_cast<const bf16x8*>(
                    &lW[((w >> 1) * 32 + ni * 16 + c16) * 64 + ks * 32 + quad * 8]);
#pragma unroll
            for (int mi = 0; mi < 4; ++mi)
#pragma unroll
                for (int ni = 0; ni < 2; ++ni)
                    acc[mi][ni] = __builtin_amdgcn_mfma_f32_16x16x32_bf16(
                        af[mi], bfr[ni], acc[mi][ni], 0, 0, 0);
        }
    }

    const int m0 = blockM + (w & 1) * 64, n0 = blockN + (w >> 1) * 32;
#pragma unroll
    for (int ni = 0; ni < 2; ++ni) {
        int n = n0 + ni * 16 + c16;
        float bv = bias[n];
#pragma unroll
        for (int mi = 0; mi < 4; ++mi) {
#pragma unroll
            for (int r = 0; r < 4; ++r) {
                int m = m0 + mi * 16 + quad * 4 + r;
                outp[(size_t)m * 1024 + n] = acc[mi][ni][r] + bv;
            }
        }
    }
}

// Flash attention v4 (unchanged from R14 — control, measured 82.0 us):
// QBLK=128, 4 waves x 32 q-rows, KVBLK=64. K/Vt fragment-linear,
// double-buffered, single barrier/iter; cvt_pk P-pack. LDS 50KB, 2/CU.
__global__ __launch_bounds__(256, 2) void attn_kernel(
    const u16* __restrict__ qh, const u16* __restrict__ kh, const u16* __restrict__ vh,
    const unsigned long long* __restrict__ pm, u16* __restrict__ ao)
{
    __shared__ __align__(16) u16 lK[2][8 * 512];    // fragment-linear, dbuf
    __shared__ __align__(16) u16 lVt[2][8 * 512];   // fragment-linear, dbuf
    __shared__ __align__(16) u16 lP[128 * 72];      // Q stage / P tile / O restage

    const int t = threadIdx.x, w = t >> 6, l = t & 63;
    const int qt = blockIdx.x, h = blockIdx.y, b = blockIdx.z;
    const int sq0 = qt * 128;
    const size_t headbase = ((size_t)(b * NH + h)) * SS * DH;
    const int quad = l >> 4, c16 = l & 15;
    const int lrow = l >> 3, lcol = (l & 7) * 8;
    const int vd2 = t & 31, vg = t >> 5;

    // ---- stage Q once (pre-scaled by 0.125*log2e at projection) ----
#pragma unroll
    for (int i = 0; i < 4; ++i) {
        int row = (w * 4 + i) * 8 + lrow;
        uint4 rq = *reinterpret_cast<const uint4*>(
            qh + headbase + (size_t)(sq0 + row) * DH + lcol);
        *reinterpret_cast<uint4*>(&lP[row * 72 + lcol]) = rq;
    }
    __asm__ volatile("s_waitcnt lgkmcnt(0)" ::: "memory");
    bf16x8 qf[2][2];
#pragma unroll
    for (int g = 0; g < 2; ++g)
#pragma unroll
        for (int ks = 0; ks < 2; ++ks)
            qf[g][ks] = *reinterpret_cast<const bf16x8*>(
                &lP[(w * 32 + g * 16 + c16) * 72 + ks * 32 + quad * 8]);

    f32x4 oAcc[2][4] = {};
    float rsumAcc[2] = {0.f, 0.f};
    const size_t pmrow0 = ((size_t)b * SS + sq0 + w * 32 + c16) * 32;
    const size_t pmrow1 = pmrow0 + 16 * 32;

    // K fragment-mapped global coords: chunk c = w*2+i, lane l ->
    // row (c>>1)*16 + c16, cols (c&1)*32 + quad*8 (u16 units)
    const int kcol = quad * 8;

    // prime kt=0 loads
    uint4 rk[2];
    unsigned int rvv[8];
    unsigned long long mw_cur0, mw_cur1, mw_next0, mw_next1;
#pragma unroll
    for (int i = 0; i < 2; ++i) {
        int c = w * 2 + i;
        rk[i] = *reinterpret_cast<const uint4*>(
            kh + headbase + (size_t)((c >> 1) * 16 + c16) * DH + (c & 1) * 32 + kcol);
    }
#pragma unroll
    for (int e = 0; e < 8; ++e)
        rvv[e] = *reinterpret_cast<const unsigned int*>(
            vh + headbase + (size_t)(vg * 8 + e) * DH + vd2 * 2);
    mw_cur0 = pm[pmrow0 + 0];
    mw_cur1 = pm[pmrow1 + 0];

    // Vt fragment write coords for this thread
    const int vchunk = (vd2 >> 3) * 2 + (vg >> 2);
    const int vlane = (vg & 3) * 16 + ((2 * vd2) & 15);

    for (int kt = 0; kt < 32; ++kt) {
        const int cur = kt & 1;
        // ---- store staged tiles into buf[cur] (no pre-barrier needed) ----
#pragma unroll
        for (int i = 0; i < 2; ++i)
            *reinterpret_cast<uint4*>(&lK[cur][(w * 2 + i) * 512 + l * 8]) = rk[i];
        {
            uint4 cA, cB;
            cA.x = __builtin_amdgcn_perm(rvv[1], rvv[0], 0x05040100);
            cA.y = __builtin_amdgcn_perm(rvv[3], rvv[2], 0x05040100);
            cA.z = __builtin_amdgcn_perm(rvv[5], rvv[4], 0x05040100);
            cA.w = __builtin_amdgcn_perm(rvv[7], rvv[6], 0x05040100);
            cB.x = __builtin_amdgcn_perm(rvv[1], rvv[0], 0x07060302);
            cB.y = __builtin_amdgcn_perm(rvv[3], rvv[2], 0x07060302);
            cB.z = __builtin_amdgcn_perm(rvv[5], rvv[4], 0x07060302);
            cB.w = __builtin_amdgcn_perm(rvv[7], rvv[6], 0x07060302);
            u16* vdst = &lVt[cur][vchunk * 512 + vlane * 8];
            *reinterpret_cast<uint4*>(vdst) = cA;       // Vt row 2*vd2
            *reinterpret_cast<uint4*>(vdst + 8) = cB;   // Vt row 2*vd2+1
        }
        __syncthreads();   // single barrier: buf[cur] visible; no global loads pending
        // ---- issue kt+1 loads (in flight through next iteration's store) ----
        {
            int ktn = (kt < 31) ? kt + 1 : kt;
            const int sk0n = ktn * 64;
#pragma unroll
            for (int i = 0; i < 2; ++i) {
                int c = w * 2 + i;
                rk[i] = *reinterpret_cast<const uint4*>(
                    kh + headbase + (size_t)(sk0n + (c >> 1) * 16 + c16) * DH +
                    (c & 1) * 32 + kcol);
            }
#pragma unroll
            for (int e = 0; e < 8; ++e)
                rvv[e] = *reinterpret_cast<const unsigned int*>(
                    vh + headbase + (size_t)(sk0n + vg * 8 + e) * DH + vd2 * 2);
            mw_next0 = pm[pmrow0 + ktn];
            mw_next1 = pm[pmrow1 + ktn];
        }

        // ---- S^T = K Q^T : lane holds S^T[sk=ni*16+quad*4+r][q=w*32+g*16+c16]
        f32x4 sAcc[2][4] = {};
        __builtin_amdgcn_s_setprio(1);
#pragma unroll
        for (int ks = 0; ks < 2; ++ks) {
#pragma unroll
            for (int ni = 0; ni < 4; ++ni) {
                bf16x8 kf = *reinterpret_cast<const bf16x8*>(
                    &lK[cur][(ni * 2 + ks) * 512 + l * 8]);
                sAcc[0][ni] = __builtin_amdgcn_mfma_f32_16x16x32_bf16(
                    kf, qf[0][ks], sAcc[0][ni], 0, 0, 0);
                sAcc[1][ni] = __builtin_amdgcn_mfma_f32_16x16x32_bf16(
                    kf, qf[1][ks], sAcc[1][ni], 0, 0, 0);
            }
        }
        __builtin_amdgcn_s_setprio(0);

        // ---- mask + exp2 + cvt_pk P store (2 groups x 4 x ds_write_b64) ----
#pragma unroll
        for (int g = 0; g < 2; ++g) {
            unsigned long long mw = g ? mw_cur1 : mw_cur0;
            unsigned long long mq = mw >> (quad * 4);
            unsigned int mlo = (unsigned int)mq, mhi = (unsigned int)(mq >> 32);
            float rs = 0.f;
#pragma unroll
            for (int ni = 0; ni < 4; ++ni) {
                unsigned int half = (ni < 2) ? mlo : mhi;
                unsigned int sh = (ni & 1) * 16;
                float p0 = ((half >> (sh + 0)) & 1u) ? EXP2f(sAcc[g][ni][0]) : 0.f;
                float p1 = ((half >> (sh + 1)) & 1u) ? EXP2f(sAcc[g][ni][1]) : 0.f;
                float p2 = ((half >> (sh + 2)) & 1u) ? EXP2f(sAcc[g][ni][2]) : 0.f;
                float p3 = ((half >> (sh + 3)) & 1u) ? EXP2f(sAcc[g][ni][3]) : 0.f;
                rs += (p0 + p1) + (p2 + p3);
                uint2 pv;
                pv.x = cvtpk_bf16(p0, p1);
                pv.y = cvtpk_bf16(p2, p3);
                *reinterpret_cast<uint2*>(
                    &lP[(w * 32 + g * 16 + c16) * 72 + ni * 16 + quad * 4]) = pv;
            }
            if (g == 0) rsumAcc[0] += rs; else rsumAcc[1] += rs;
        }
        mw_cur0 = mw_next0; mw_cur1 = mw_next1;
        // wave-private lP RAW: drain DS queue, no cross-wave barrier needed
        __asm__ volatile("s_waitcnt lgkmcnt(0)" ::: "memory");

        // ---- O += P @ V : vf reads lane-linear; each feeds both q-groups ----
        __builtin_amdgcn_s_setprio(1);
#pragma unroll
        for (int ks = 0; ks < 2; ++ks) {
            bf16x8 pf0 = *reinterpret_cast<const bf16x8*>(
                &lP[(w * 32 + c16) * 72 + ks * 32 + quad * 8]);
            bf16x8 pf1 = *reinterpret_cast<const bf16x8*>(
                &lP[(w * 32 + 16 + c16) * 72 + ks * 32 + quad * 8]);
#pragma unroll
            for (int no = 0; no < 4; ++no) {
                bf16x8 vf = *reinterpret_cast<const bf16x8*>(
                    &lVt[cur][(no * 2 + ks) * 512 + l * 8]);
                oAcc[0][no] = __builtin_amdgcn_mfma_f32_16x16x32_bf16(
                    pf0, vf, oAcc[0][no], 0, 0, 0);
                oAcc[1][no] = __builtin_amdgcn_mfma_f32_16x16x32_bf16(
                    pf1, vf, oAcc[1][no], 0, 0, 0);
            }
        }
        __builtin_amdgcn_s_setprio(0);
    }

    // ---- epilogue: row-sum reduce, normalize, restage O in lP, write ----
    float linv[2][4];
#pragma unroll
    for (int g = 0; g < 2; ++g) {
        float s = (g == 0) ? rsumAcc[0] : rsumAcc[1];
        s += __shfl_xor(s, 16);
        s += __shfl_xor(s, 32);
        float rinv = 1.0f / s;
#pragma unroll
        for (int r = 0; r < 4; ++r)
            linv[g][r] = __shfl(rinv, quad * 4 + r);
    }
    // O writes hit wave-private lP rows; PV's pf reads already completed
#pragma unroll
    for (int g = 0; g < 2; ++g)
#pragma unroll
        for (int no = 0; no < 4; ++no)
#pragma unroll
            for (int r = 0; r < 4; ++r)
                lP[(w * 32 + g * 16 + quad * 4 + r) * 72 + no * 16 + c16] =
                    f2bf_fast(oAcc[g][no][r] * linv[g][r]);
    __syncthreads();
#pragma unroll
    for (int i = 0; i < 4; ++i) {
        int idx = t + i * 256;
        int row = idx >> 3, ch = idx & 7;
        uint4 val = *reinterpret_cast<const uint4*>(&lP[row * 72 + ch * 8]);
        *reinterpret_cast<uint4*>(
            ao + ((size_t)b * SS + sq0 + row) * D_MODEL + h * DH + ch * 8) = val;
    }
}

extern "C" void kernel_launch(void* const* d_in, const int* in_sizes, int n_in,
                              void* d_out, int out_size, void* d_ws, size_t ws_size,
                              hipStream_t stream)
{
    const float* q    = (const float*)d_in[0];
    const float* k    = (const float*)d_in[1];
    const float* v    = (const float*)d_in[2];
    const int*   mask = (const int*)d_in[3];
    const float* Wq   = (const float*)d_in[4];
    const float* bq   = (const float*)d_in[5];
    const float* Wk   = (const float*)d_in[6];
    const float* bk   = (const float*)d_in[7];
    const float* Wv   = (const float*)d_in[8];
    const float* bv   = (const float*)d_in[9];
    const float* Wo   = (const float*)d_in[10];
    const float* bo   = (const float*)d_in[11];

    const size_t T4M = (size_t)BB * SS * D_MODEL;  // 4,194,304 elems
    u16* qh = (u16*)d_ws;                          // [B][NH][S][DH] bf16 (Q pre-scaled)
    u16* kh = qh + T4M;
    u16* vh = kh + T4M;
    u16* ao = vh + T4M;                            // [B][S][D] bf16
    u16* cW = ao + T4M;                            // 4 x 1M bf16 (Wq,Wk,Wv,Wo)
    u16* qb = cW + 4 * (size_t)D_MODEL * D_MODEL;  // q,k,v as bf16 (3 x 4M)
    unsigned long long* pm = (unsigned long long*)(qb + 3 * T4M);
    float* out = (float*)d_out;

    prep_kernel<<<9216, 256, 0, stream>>>(Wq, Wk, Wv, Wo, cW, q, k, v, qb, mask, pm);
    qkv_kernel<<<dim3(32, 8, 3), 256, 0, stream>>>(qb, cW, bq, bk, bv, qh, kh, vh);
    attn_kernel<<<dim3(16, NH, BB), 256, 0, stream>>>(qh, kh, vh, pm, ao);
    oproj_kernel<<<dim3(32, 16), 256, 0, stream>>>(ao, cW + 3 * (size_t)D_MODEL * D_MODEL, bo, out);
}